// Round 5
// baseline (3427.324 us; speedup 1.0000x reference)
//
#include <hip/hip_runtime.h>

// Wave-level LDS ordering fence: waits all outstanding LDS ops; "memory"
// clobber stops compiler reordering LDS accesses across it. Waves are fully
// independent (per-wave LDS slots, no shared weights in LDS) -> no barriers.
#define FENCE() asm volatile("s_waitcnt lgkmcnt(0)" ::: "memory")

__device__ __forceinline__ float fshfl_xor(float v, int m) {
  return __shfl_xor(v, m, 64);
}

// One block = 256 threads = 4 waves, one 32x32 SPD matrix per wave.
// All-fp32. Stage-3 = one-sided Jacobi on the 16x4 factor; eigenvectors of
// M3 = Q^T Q are the ACCUMULATED ROTATIONS J (not the normalized columns --
// those are the left singular vectors; round-4 bug).
// LDS: 4*1568*4 = 25088 B/block -> 6 blocks/CU; VGPR<=64 -> 24 waves/CU.
__global__ __launch_bounds__(256, 8) void spd_fused(
    const float* __restrict__ xg,
    const float* __restrict__ w1g,
    const float* __restrict__ w2g,
    const float* __restrict__ w3g,
    const float* __restrict__ fcg,
    float* __restrict__ outg,
    int B)
{
  __shared__ float slot[4][1568];

  const int tid  = threadIdx.x;
  const int wid  = tid >> 6;
  const int lane = tid & 63;

  float* Cc  = slot[wid];          // 1024: x -> M1(swizzled cols) -> M2/V2 (stride 17)
  float* Pb  = slot[wid] + 1024;   // 512:  P (32x16) -> stage-3 J/lw scratch
  float* dcl = slot[wid] + 1536;   // 32:   clamped stage-1 eigenvalues

  const long b = (long)blockIdx.x * 4 + wid;
  if (b >= B) return;

  // ---------------- load x -> Cc row-major [32][32]
  {
    const float4* xv = (const float4*)(xg + (size_t)b * 1024);
    float4* c4 = (float4*)Cc;
    #pragma unroll
    for (int jj = 0; jj < 4; ++jj) {
      int i4 = lane + 64 * jj;
      c4[i4] = xv[i4];
    }
  }
  FENCE();

  const int j = lane & 31;
  const int h = lane >> 5;

  // ---------------- Tmat = x * w1 in registers. T[e] = Tmat[16h+e][j].
  // Uses x symmetry: x[r][c] == x[c][r] -> read x rows as float4.
  float T[16];
  {
    #pragma unroll
    for (int e = 0; e < 16; ++e) T[e] = 0.f;
    const float4* c4 = (const float4*)Cc;
    #pragma unroll 4
    for (int c = 0; c < 32; ++c) {
      float wv = w1g[c * 32 + j];
      float4 x0 = c4[c * 8 + h * 4 + 0];
      float4 x1 = c4[c * 8 + h * 4 + 1];
      float4 x2 = c4[c * 8 + h * 4 + 2];
      float4 x3 = c4[c * 8 + h * 4 + 3];
      T[0]  += x0.x * wv; T[1]  += x0.y * wv; T[2]  += x0.z * wv; T[3]  += x0.w * wv;
      T[4]  += x1.x * wv; T[5]  += x1.y * wv; T[6]  += x1.z * wv; T[7]  += x1.w * wv;
      T[8]  += x2.x * wv; T[9]  += x2.y * wv; T[10] += x2.z * wv; T[11] += x2.w * wv;
      T[12] += x3.x * wv; T[13] += x3.y * wv; T[14] += x3.z * wv; T[15] += x3.w * wv;
    }
  }
  FENCE();   // all x reads complete before M1 overwrites Cc

  // ---------------- M1 = w1^T * Tmat -> Cc swizzled-quad column-major.
  // Column p, quad qd lives at p*32 + ((qd+p)&7)*4. Outer product over r
  // (r = 16h+e handled by this lane), halves combined via shfl_xor(32).
  {
    const float4* w14 = (const float4*)w1g;   // row r = w14[r*8 + 0..7]
    #pragma unroll
    for (int ih2 = 0; ih2 < 4; ++ih2) {       // i = 8*ih2 + u
      float acc[8];
      #pragma unroll
      for (int u = 0; u < 8; ++u) acc[u] = 0.f;
      #pragma unroll
      for (int e = 0; e < 16; ++e) {
        int r = 16 * h + e;
        float4 wA = w14[r * 8 + ih2 * 2];
        float4 wB = w14[r * 8 + ih2 * 2 + 1];
        float tv = T[e];
        acc[0] += wA.x * tv; acc[1] += wA.y * tv; acc[2] += wA.z * tv; acc[3] += wA.w * tv;
        acc[4] += wB.x * tv; acc[5] += wB.y * tv; acc[6] += wB.z * tv; acc[7] += wB.w * tv;
      }
      #pragma unroll
      for (int u = 0; u < 8; ++u) acc[u] += fshfl_xor(acc[u], 32);
      if (h == (ih2 & 1)) {
        int qd0 = 2 * ih2, qd1 = 2 * ih2 + 1;
        *(float4*)(Cc + j * 32 + (((qd0 + j) & 7) << 2)) =
            make_float4(acc[0], acc[1], acc[2], acc[3]);
        *(float4*)(Cc + j * 32 + (((qd1 + j) & 7) << 2)) =
            make_float4(acc[4], acc[5], acc[6], acc[7]);
      }
    }
  }
  FENCE();

  // ---------------- one-sided Jacobi, n=32 (16 pairs/round, 4 lanes/pair)
  {
    const int g4 = lane >> 2;
    const int c2 = (lane & 3) << 1;   // this lane handles quads c2, c2+1
    #pragma unroll 1
    for (int sweep = 0; sweep < 10; ++sweep) {
      float offmax = 0.f;
      #pragma unroll 1
      for (int r = 0; r < 31; ++r) {
        int p, q;
        if (g4 == 0) { p = 31; q = r; }
        else { p = (r + g4) % 31; q = (r + 31 - g4) % 31; }
        const int pa0 = p * 32 + (((c2 + p) & 7) << 2);
        const int pa1 = p * 32 + (((c2 + 1 + p) & 7) << 2);
        const int qa0 = q * 32 + (((c2 + q) & 7) << 2);
        const int qa1 = q * 32 + (((c2 + 1 + q) & 7) << 2);
        float4 a0 = *(const float4*)(Cc + pa0);
        float4 a1 = *(const float4*)(Cc + pa1);
        float4 b0 = *(const float4*)(Cc + qa0);
        float4 b1 = *(const float4*)(Cc + qa1);
        float sa = a0.x*a0.x + a0.y*a0.y + a0.z*a0.z + a0.w*a0.w
                 + a1.x*a1.x + a1.y*a1.y + a1.z*a1.z + a1.w*a1.w;
        float sb = b0.x*b0.x + b0.y*b0.y + b0.z*b0.z + b0.w*b0.w
                 + b1.x*b1.x + b1.y*b1.y + b1.z*b1.z + b1.w*b1.w;
        float sg = a0.x*b0.x + a0.y*b0.y + a0.z*b0.z + a0.w*b0.w
                 + a1.x*b1.x + a1.y*b1.y + a1.z*b1.z + a1.w*b1.w;
        sa += fshfl_xor(sa, 1); sb += fshfl_xor(sb, 1); sg += fshfl_xor(sg, 1);
        sa += fshfl_xor(sa, 2); sb += fshfl_xor(sb, 2); sg += fshfl_xor(sg, 2);
        float dn  = sa * sb;
        float rel = (dn > 0.f) ? (sg * sg) / dn : 0.f;
        offmax = fmaxf(offmax, rel);
        if (rel > 1e-13f) {
          float u  = 0.5f * (sb - sa);
          float R  = sqrtf(u * u + sg * sg);
          float t  = sg / (u + ((u >= 0.f) ? R : -R));
          float ct = rsqrtf(1.f + t * t);
          float st = ct * t;
          float4 n0, n1, m0, m1;
          n0.x = ct*a0.x - st*b0.x;  m0.x = st*a0.x + ct*b0.x;
          n0.y = ct*a0.y - st*b0.y;  m0.y = st*a0.y + ct*b0.y;
          n0.z = ct*a0.z - st*b0.z;  m0.z = st*a0.z + ct*b0.z;
          n0.w = ct*a0.w - st*b0.w;  m0.w = st*a0.w + ct*b0.w;
          n1.x = ct*a1.x - st*b1.x;  m1.x = st*a1.x + ct*b1.x;
          n1.y = ct*a1.y - st*b1.y;  m1.y = st*a1.y + ct*b1.y;
          n1.z = ct*a1.z - st*b1.z;  m1.z = st*a1.z + ct*b1.z;
          n1.w = ct*a1.w - st*b1.w;  m1.w = st*a1.w + ct*b1.w;
          *(float4*)(Cc + pa0) = n0; *(float4*)(Cc + pa1) = n1;
          *(float4*)(Cc + qa0) = m0; *(float4*)(Cc + qa1) = m1;
        }
        FENCE();
      }
      #pragma unroll
      for (int m = 1; m <= 32; m <<= 1) offmax = fmaxf(offmax, fshfl_xor(offmax, m));
      if (offmax < 1e-12f) break;
    }
  }

  // ---------------- lambda_1 + ReEig clamp; keep own column in registers
  const int k1 = lane & 31;     // both half-waves redundantly handle column k1
  float col[32];
  float inv1;
  {
    float ss = 0.f;
    #pragma unroll
    for (int qd = 0; qd < 8; ++qd) {
      float4 v = *(const float4*)(Cc + k1 * 32 + (((qd + k1) & 7) << 2));
      col[4*qd+0] = v.x; col[4*qd+1] = v.y; col[4*qd+2] = v.z; col[4*qd+3] = v.w;
      ss += v.x*v.x + v.y*v.y + v.z*v.z + v.w*v.w;
    }
    float lam = sqrtf(ss);
    inv1 = (lam > 0.f) ? (1.f / lam) : 0.f;
    if (lane < 32) dcl[k1] = fmaxf(lam, 1e-4f);
  }

  // ---------------- P = V1^T w2 -> Pb (32x16, stride 16)
  {
    const int jb4 = (lane >> 5) * 2;          // float4 col-block: jb = jb4*4
    const float4* w24 = (const float4*)w2g;   // row r = w24[r*4 + 0..3]
    float acc[8];
    #pragma unroll
    for (int u = 0; u < 8; ++u) acc[u] = 0.f;
    #pragma unroll
    for (int r = 0; r < 32; ++r) {
      float4 wA = w24[r * 4 + jb4];
      float4 wB = w24[r * 4 + jb4 + 1];
      float cv = col[r];
      acc[0] += wA.x * cv; acc[1] += wA.y * cv; acc[2] += wA.z * cv; acc[3] += wA.w * cv;
      acc[4] += wB.x * cv; acc[5] += wB.y * cv; acc[6] += wB.z * cv; acc[7] += wB.w * cv;
    }
    #pragma unroll
    for (int u = 0; u < 8; ++u) acc[u] *= inv1;
    *(float4*)(Pb + k1 * 16 + jb4 * 4)     = make_float4(acc[0], acc[1], acc[2], acc[3]);
    *(float4*)(Pb + k1 * 16 + jb4 * 4 + 4) = make_float4(acc[4], acc[5], acc[6], acc[7]);
  }
  FENCE();

  // ---------------- M2 = P^T diag(d1) P -> Cc col-major (stride 17)
  {
    const int i0 = lane >> 4;     // 0..3
    const int j2 = lane & 15;
    float pj[32];
    #pragma unroll
    for (int kk = 0; kk < 32; ++kk)
      pj[kk] = Pb[kk * 16 + j2] * dcl[kk];
    float m2[4] = {0.f, 0.f, 0.f, 0.f};
    #pragma unroll
    for (int kk = 0; kk < 32; ++kk) {
      #pragma unroll
      for (int e = 0; e < 4; ++e)
        m2[e] += pj[kk] * Pb[kk * 16 + (e << 2) + i0];
    }
    #pragma unroll
    for (int e = 0; e < 4; ++e)
      Cc[j2 * 17 + (e << 2) + i0] = m2[e];
  }
  FENCE();

  // ---------------- one-sided Jacobi, n=16 (8 pairs/round, 8 lanes/pair)
  {
    const int g8 = lane >> 3;
    const int rb = (lane & 7) * 2;
    #pragma unroll 1
    for (int sweep = 0; sweep < 8; ++sweep) {
      float offmax = 0.f;
      #pragma unroll 1
      for (int r = 0; r < 15; ++r) {
        int p, q;
        if (g8 == 0) { p = 15; q = r; }
        else { p = (r + g8) % 15; q = (r + 15 - g8) % 15; }
        float a0 = Cc[p * 17 + rb], a1 = Cc[p * 17 + rb + 1];
        float c0 = Cc[q * 17 + rb], c1 = Cc[q * 17 + rb + 1];
        float sa = a0 * a0 + a1 * a1;
        float sb = c0 * c0 + c1 * c1;
        float sg = a0 * c0 + a1 * c1;
        sa += fshfl_xor(sa, 1); sb += fshfl_xor(sb, 1); sg += fshfl_xor(sg, 1);
        sa += fshfl_xor(sa, 2); sb += fshfl_xor(sb, 2); sg += fshfl_xor(sg, 2);
        sa += fshfl_xor(sa, 4); sb += fshfl_xor(sb, 4); sg += fshfl_xor(sg, 4);
        float dn  = sa * sb;
        float rel = (dn > 0.f) ? (sg * sg) / dn : 0.f;
        offmax = fmaxf(offmax, rel);
        if (rel > 1e-13f) {
          float u  = 0.5f * (sb - sa);
          float R  = sqrtf(u * u + sg * sg);
          float t  = sg / (u + ((u >= 0.f) ? R : -R));
          float ct = rsqrtf(1.f + t * t);
          float st = ct * t;
          Cc[p * 17 + rb]     = ct * a0 - st * c0;
          Cc[p * 17 + rb + 1] = ct * a1 - st * c1;
          Cc[q * 17 + rb]     = st * a0 + ct * c0;
          Cc[q * 17 + rb + 1] = st * a1 + ct * c1;
        }
        FENCE();
      }
      #pragma unroll
      for (int m = 1; m <= 32; m <<= 1) offmax = fmaxf(offmax, fshfl_xor(offmax, m));
      if (offmax < 1e-12f) break;
    }
  }

  // ---------------- Qb[k][j] = (V2^T w3)[k][j] * sqrt(clamp(lam2_k)) in regs
  // lane = (kq = lane>>2, jq = lane&3); per-lane norm of its column kq.
  float qv;
  const int kq = lane >> 2;
  const int jq = lane & 3;
  {
    float accq = 0.f, ss = 0.f;
    #pragma unroll
    for (int r = 0; r < 16; ++r) {
      float v = Cc[kq * 17 + r];
      accq += v * w3g[r * 4 + jq];
      ss   += v * v;
    }
    float lam = sqrtf(ss);
    float scl = ((lam > 0.f) ? (1.f / lam) : 0.f) * sqrtf(fmaxf(lam, 1e-4f));
    qv = accq * scl;
  }

  // ---------------- stage 3: one-sided Jacobi ON THE 16x4 FACTOR, with
  // accumulated rotations J. M3 = Q^T Q = J Sigma^2 J^T -> eigenvectors are
  // the columns of J (NOT the normalized rotated columns = left sing. vecs).
  // J[kq][jq] per lane (kq<4 meaningful); P^Q masks {1,2,3} stay in-kq-group.
  float jv = (kq == jq) ? 1.f : 0.f;
  {
    #define ROT3(P_, Q_) do {                                             \
      float w_ = fshfl_xor(qv, (P_) ^ (Q_));                              \
      float s1 = qv * qv, s2 = w_ * w_, s3 = qv * w_;                     \
      s1 += fshfl_xor(s1, 4);  s2 += fshfl_xor(s2, 4);  s3 += fshfl_xor(s3, 4);  \
      s1 += fshfl_xor(s1, 8);  s2 += fshfl_xor(s2, 8);  s3 += fshfl_xor(s3, 8);  \
      s1 += fshfl_xor(s1, 16); s2 += fshfl_xor(s2, 16); s3 += fshfl_xor(s3, 16); \
      s1 += fshfl_xor(s1, 32); s2 += fshfl_xor(s2, 32); s3 += fshfl_xor(s3, 32); \
      bool isp = (jq == (P_)), isq = (jq == (Q_));                        \
      float sa = isp ? s1 : s2;                                           \
      float sb = isp ? s2 : s1;                                           \
      float u_ = 0.5f * (sb - sa);                                        \
      float R_ = sqrtf(u_ * u_ + s3 * s3);                                \
      float dn_ = u_ + copysignf(fmaxf(R_, 1e-30f), u_);                  \
      float t_ = s3 / dn_;                                                \
      float ct = rsqrtf(1.f + t_ * t_);                                   \
      float st = ct * t_;                                                 \
      float wj_ = fshfl_xor(jv, (P_) ^ (Q_));                             \
      float nv  = isp ? (ct * qv - st * w_)  : (st * w_  + ct * qv);      \
      float nvj = isp ? (ct * jv - st * wj_) : (st * wj_ + ct * jv);      \
      if (isp | isq) { qv = nv; jv = nvj; }                               \
    } while (0)

    #pragma unroll 1
    for (int sweep = 0; sweep < 6; ++sweep) {
      ROT3(0,1); ROT3(2,3); ROT3(0,2); ROT3(1,3); ROT3(0,3); ROT3(1,2);
    }
    #undef ROT3
  }

  // ---------------- lambda_3 = ||col||^2, LogEig via J, FC, log_softmax
  {
    float ss = qv * qv;
    ss += fshfl_xor(ss, 4); ss += fshfl_xor(ss, 8);
    ss += fshfl_xor(ss, 16); ss += fshfl_xor(ss, 32);
    float lwv = logf(fmaxf(ss, 1e-10f));       // log eigenvalue of column jq
    if (kq < 4)  Pb[kq * 4 + jq] = jv;         // J, row-major 4x4
    if (kq == 0) Pb[16 + jq] = lwv;            // lanes 0..3: per-column loglam
    FENCE();

    float f = 0.f;
    if (lane < 16) {
      int i3 = lane >> 2, j3 = lane & 3;
      #pragma unroll
      for (int c = 0; c < 4; ++c)
        f += Pb[16 + c] * Pb[i3 * 4 + c] * Pb[j3 * 4 + c];
    }
    float t0 = 0.f, t1 = 0.f;
    if (lane < 16) { t0 = f * fcg[2 * lane]; t1 = f * fcg[2 * lane + 1]; }
    t0 += fshfl_xor(t0, 1); t1 += fshfl_xor(t1, 1);
    t0 += fshfl_xor(t0, 2); t1 += fshfl_xor(t1, 2);
    t0 += fshfl_xor(t0, 4); t1 += fshfl_xor(t1, 4);
    t0 += fshfl_xor(t0, 8); t1 += fshfl_xor(t1, 8);
    float mx  = fmaxf(t0, t1);
    float lse = mx + logf(expf(t0 - mx) + expf(t1 - mx));

    float* outFeat = outg + (size_t)B * 2;
    if (lane < 16) outFeat[(size_t)b * 16 + lane] = f;
    if (lane < 2)  outg[(size_t)b * 2 + lane] = (lane == 0 ? t0 : t1) - lse;
  }
}

extern "C" void kernel_launch(void* const* d_in, const int* in_sizes, int n_in,
                              void* d_out, int out_size, void* d_ws, size_t ws_size,
                              hipStream_t stream) {
  const float* x  = (const float*)d_in[0];
  const float* w1 = (const float*)d_in[1];
  const float* w2 = (const float*)d_in[2];
  const float* w3 = (const float*)d_in[3];
  const float* fc = (const float*)d_in[4];
  float* out = (float*)d_out;
  int B = in_sizes[0] / 1024;
  int grid = (B + 3) / 4;
  hipLaunchKernelGGL(spd_fused, dim3(grid), dim3(256), 0, stream,
                     x, w1, w2, w3, fc, out, B);
}

// Round 6
// 3133.000 us; speedup vs baseline: 1.0939x; 1.0939x over previous
//
#include <hip/hip_runtime.h>

// Wave-level LDS ordering fence: waits all outstanding LDS ops; "memory"
// clobber stops compiler reordering LDS accesses across it. Waves are fully
// independent (per-wave LDS slots, no shared weights in LDS) -> no barriers.
#define FENCE() asm volatile("s_waitcnt lgkmcnt(0)" ::: "memory")

__device__ __forceinline__ float fshfl_xor(float v, int m) {
  return __shfl_xor(v, m, 64);
}

// One block = 256 threads = 4 waves, one 32x32 SPD matrix per wave.
// All-fp32. Stage-3 = one-sided Jacobi on the 16x4 factor with accumulated
// rotations J (eigenvectors of Q^T Q).
// VGPR diet vs r5: no col[32]/pj[32] register arrays; P stored pre-scaled by
// sqrt(clamped lambda1) so M2 = Ps^T Ps needs no diagonal array; unrolls
// capped so global weight loads don't pile up in VGPRs.
// LDS: 4*1536*4 = 24576 B/block -> 6 blocks/CU; VGPR<=64 -> 24 waves/CU.
__global__ __launch_bounds__(256, 8) void spd_fused(
    const float* __restrict__ xg,
    const float* __restrict__ w1g,
    const float* __restrict__ w2g,
    const float* __restrict__ w3g,
    const float* __restrict__ fcg,
    float* __restrict__ outg,
    int B)
{
  __shared__ float slot[4][1536];

  const int tid  = threadIdx.x;
  const int wid  = tid >> 6;
  const int lane = tid & 63;

  float* Cc = slot[wid];          // 1024: x -> M1(swizzled cols) -> M2/V2 (stride 17)
  float* Pb = slot[wid] + 1024;   // 512:  Ps (32x16) -> stage-3 J/lw scratch

  const long b = (long)blockIdx.x * 4 + wid;
  if (b >= B) return;

  // ---------------- load x -> Cc row-major [32][32]
  {
    const float4* xv = (const float4*)(xg + (size_t)b * 1024);
    float4* c4 = (float4*)Cc;
    #pragma unroll
    for (int jj = 0; jj < 4; ++jj) {
      int i4 = lane + 64 * jj;
      c4[i4] = xv[i4];
    }
  }
  FENCE();

  const int j = lane & 31;
  const int h = lane >> 5;

  // ---------------- Tmat = x * w1 in registers. T[e] = Tmat[16h+e][j].
  // Uses x symmetry: x[r][c] == x[c][r] -> read x rows as float4.
  float T[16];
  {
    #pragma unroll
    for (int e = 0; e < 16; ++e) T[e] = 0.f;
    const float4* c4 = (const float4*)Cc;
    #pragma unroll 4
    for (int c = 0; c < 32; ++c) {
      float wv = w1g[c * 32 + j];
      float4 x0 = c4[c * 8 + h * 4 + 0];
      float4 x1 = c4[c * 8 + h * 4 + 1];
      float4 x2 = c4[c * 8 + h * 4 + 2];
      float4 x3 = c4[c * 8 + h * 4 + 3];
      T[0]  += x0.x * wv; T[1]  += x0.y * wv; T[2]  += x0.z * wv; T[3]  += x0.w * wv;
      T[4]  += x1.x * wv; T[5]  += x1.y * wv; T[6]  += x1.z * wv; T[7]  += x1.w * wv;
      T[8]  += x2.x * wv; T[9]  += x2.y * wv; T[10] += x2.z * wv; T[11] += x2.w * wv;
      T[12] += x3.x * wv; T[13] += x3.y * wv; T[14] += x3.z * wv; T[15] += x3.w * wv;
    }
  }
  FENCE();   // all x reads complete before M1 overwrites Cc

  // ---------------- M1 = w1^T * Tmat -> Cc swizzled-quad column-major.
  // Column p, quad qd lives at p*32 + ((qd+p)&7)*4. Outer product over r
  // (r = 16h+e handled by this lane), halves combined via shfl_xor(32).
  {
    const float4* w14 = (const float4*)w1g;   // row r = w14[r*8 + 0..7]
    #pragma unroll
    for (int ih2 = 0; ih2 < 4; ++ih2) {       // i = 8*ih2 + u
      float acc[8];
      #pragma unroll
      for (int u = 0; u < 8; ++u) acc[u] = 0.f;
      #pragma unroll 4
      for (int e = 0; e < 16; ++e) {
        int r = 16 * h + e;
        float4 wA = w14[r * 8 + ih2 * 2];
        float4 wB = w14[r * 8 + ih2 * 2 + 1];
        float tv = T[e];
        acc[0] += wA.x * tv; acc[1] += wA.y * tv; acc[2] += wA.z * tv; acc[3] += wA.w * tv;
        acc[4] += wB.x * tv; acc[5] += wB.y * tv; acc[6] += wB.z * tv; acc[7] += wB.w * tv;
      }
      #pragma unroll
      for (int u = 0; u < 8; ++u) acc[u] += fshfl_xor(acc[u], 32);
      if (h == (ih2 & 1)) {
        int qd0 = 2 * ih2, qd1 = 2 * ih2 + 1;
        *(float4*)(Cc + j * 32 + (((qd0 + j) & 7) << 2)) =
            make_float4(acc[0], acc[1], acc[2], acc[3]);
        *(float4*)(Cc + j * 32 + (((qd1 + j) & 7) << 2)) =
            make_float4(acc[4], acc[5], acc[6], acc[7]);
      }
    }
  }
  FENCE();

  // ---------------- one-sided Jacobi, n=32 (16 pairs/round, 4 lanes/pair)
  {
    const int g4 = lane >> 2;
    const int c2 = (lane & 3) << 1;   // this lane handles quads c2, c2+1
    #pragma unroll 1
    for (int sweep = 0; sweep < 10; ++sweep) {
      float offmax = 0.f;
      #pragma unroll 1
      for (int r = 0; r < 31; ++r) {
        int p, q;
        if (g4 == 0) { p = 31; q = r; }
        else { p = (r + g4) % 31; q = (r + 31 - g4) % 31; }
        const int pa0 = p * 32 + (((c2 + p) & 7) << 2);
        const int pa1 = p * 32 + (((c2 + 1 + p) & 7) << 2);
        const int qa0 = q * 32 + (((c2 + q) & 7) << 2);
        const int qa1 = q * 32 + (((c2 + 1 + q) & 7) << 2);
        float4 a0 = *(const float4*)(Cc + pa0);
        float4 a1 = *(const float4*)(Cc + pa1);
        float4 b0 = *(const float4*)(Cc + qa0);
        float4 b1 = *(const float4*)(Cc + qa1);
        float sa = a0.x*a0.x + a0.y*a0.y + a0.z*a0.z + a0.w*a0.w
                 + a1.x*a1.x + a1.y*a1.y + a1.z*a1.z + a1.w*a1.w;
        float sb = b0.x*b0.x + b0.y*b0.y + b0.z*b0.z + b0.w*b0.w
                 + b1.x*b1.x + b1.y*b1.y + b1.z*b1.z + b1.w*b1.w;
        float sg = a0.x*b0.x + a0.y*b0.y + a0.z*b0.z + a0.w*b0.w
                 + a1.x*b1.x + a1.y*b1.y + a1.z*b1.z + a1.w*b1.w;
        sa += fshfl_xor(sa, 1); sb += fshfl_xor(sb, 1); sg += fshfl_xor(sg, 1);
        sa += fshfl_xor(sa, 2); sb += fshfl_xor(sb, 2); sg += fshfl_xor(sg, 2);
        float dn  = sa * sb;
        float rel = (dn > 0.f) ? (sg * sg) / dn : 0.f;
        offmax = fmaxf(offmax, rel);
        if (rel > 1e-13f) {
          float u  = 0.5f * (sb - sa);
          float R  = sqrtf(u * u + sg * sg);
          float t  = sg / (u + ((u >= 0.f) ? R : -R));
          float ct = rsqrtf(1.f + t * t);
          float st = ct * t;
          float4 n0, n1, m0, m1;
          n0.x = ct*a0.x - st*b0.x;  m0.x = st*a0.x + ct*b0.x;
          n0.y = ct*a0.y - st*b0.y;  m0.y = st*a0.y + ct*b0.y;
          n0.z = ct*a0.z - st*b0.z;  m0.z = st*a0.z + ct*b0.z;
          n0.w = ct*a0.w - st*b0.w;  m0.w = st*a0.w + ct*b0.w;
          n1.x = ct*a1.x - st*b1.x;  m1.x = st*a1.x + ct*b1.x;
          n1.y = ct*a1.y - st*b1.y;  m1.y = st*a1.y + ct*b1.y;
          n1.z = ct*a1.z - st*b1.z;  m1.z = st*a1.z + ct*b1.z;
          n1.w = ct*a1.w - st*b1.w;  m1.w = st*a1.w + ct*b1.w;
          *(float4*)(Cc + pa0) = n0; *(float4*)(Cc + pa1) = n1;
          *(float4*)(Cc + qa0) = m0; *(float4*)(Cc + qa1) = m1;
        }
        FENCE();
      }
      #pragma unroll
      for (int m = 1; m <= 32; m <<= 1) offmax = fmaxf(offmax, fshfl_xor(offmax, m));
      if (offmax < 1e-12f) break;
    }
  }

  // ---------------- lambda_1 + ReEig + Ps = sqrt(clamp(lam1))*v1hat^T w2,
  // fused single pass over the column's 8 quads (no col[] register array).
  // Ps -> Pb (32x16, stride 16); M2 = Ps^T Ps later (diagonal folded in).
  {
    const int k1  = lane & 31;              // column owned by this lane
    const int jb4 = (lane >> 5) * 2;        // float4 col-block: jb = jb4*4
    const float4* w24 = (const float4*)w2g; // row r = w24[r*4 + 0..3]
    float acc[8];
    #pragma unroll
    for (int u = 0; u < 8; ++u) acc[u] = 0.f;
    float ss = 0.f;
    #pragma unroll 2
    for (int qd = 0; qd < 8; ++qd) {
      float4 v = *(const float4*)(Cc + k1 * 32 + (((qd + k1) & 7) << 2));
      ss += v.x*v.x + v.y*v.y + v.z*v.z + v.w*v.w;
      const int r0 = qd << 2;
      float4 wA, wB;
      wA = w24[(r0 + 0) * 4 + jb4]; wB = w24[(r0 + 0) * 4 + jb4 + 1];
      acc[0] += v.x * wA.x; acc[1] += v.x * wA.y; acc[2] += v.x * wA.z; acc[3] += v.x * wA.w;
      acc[4] += v.x * wB.x; acc[5] += v.x * wB.y; acc[6] += v.x * wB.z; acc[7] += v.x * wB.w;
      wA = w24[(r0 + 1) * 4 + jb4]; wB = w24[(r0 + 1) * 4 + jb4 + 1];
      acc[0] += v.y * wA.x; acc[1] += v.y * wA.y; acc[2] += v.y * wA.z; acc[3] += v.y * wA.w;
      acc[4] += v.y * wB.x; acc[5] += v.y * wB.y; acc[6] += v.y * wB.z; acc[7] += v.y * wB.w;
      wA = w24[(r0 + 2) * 4 + jb4]; wB = w24[(r0 + 2) * 4 + jb4 + 1];
      acc[0] += v.z * wA.x; acc[1] += v.z * wA.y; acc[2] += v.z * wA.z; acc[3] += v.z * wA.w;
      acc[4] += v.z * wB.x; acc[5] += v.z * wB.y; acc[6] += v.z * wB.z; acc[7] += v.z * wB.w;
      wA = w24[(r0 + 3) * 4 + jb4]; wB = w24[(r0 + 3) * 4 + jb4 + 1];
      acc[0] += v.w * wA.x; acc[1] += v.w * wA.y; acc[2] += v.w * wA.z; acc[3] += v.w * wA.w;
      acc[4] += v.w * wB.x; acc[5] += v.w * wB.y; acc[6] += v.w * wB.z; acc[7] += v.w * wB.w;
    }
    float lam = sqrtf(ss);
    float sc1 = (lam > 0.f) ? (sqrtf(fmaxf(lam, 1e-4f)) / lam) : 0.f;
    #pragma unroll
    for (int u = 0; u < 8; ++u) acc[u] *= sc1;
    *(float4*)(Pb + k1 * 16 + jb4 * 4)     = make_float4(acc[0], acc[1], acc[2], acc[3]);
    *(float4*)(Pb + k1 * 16 + jb4 * 4 + 4) = make_float4(acc[4], acc[5], acc[6], acc[7]);
  }
  FENCE();

  // ---------------- M2 = Ps^T Ps -> Cc col-major (stride 17)
  {
    const int i0 = lane >> 4;     // 0..3
    const int j2 = lane & 15;
    float m2[4] = {0.f, 0.f, 0.f, 0.f};
    #pragma unroll 4
    for (int kk = 0; kk < 32; ++kk) {
      float pv = Pb[kk * 16 + j2];
      #pragma unroll
      for (int e = 0; e < 4; ++e)
        m2[e] += pv * Pb[kk * 16 + (e << 2) + i0];
    }
    #pragma unroll
    for (int e = 0; e < 4; ++e)
      Cc[j2 * 17 + (e << 2) + i0] = m2[e];
  }
  FENCE();

  // ---------------- one-sided Jacobi, n=16 (8 pairs/round, 8 lanes/pair)
  {
    const int g8 = lane >> 3;
    const int rb = (lane & 7) * 2;
    #pragma unroll 1
    for (int sweep = 0; sweep < 8; ++sweep) {
      float offmax = 0.f;
      #pragma unroll 1
      for (int r = 0; r < 15; ++r) {
        int p, q;
        if (g8 == 0) { p = 15; q = r; }
        else { p = (r + g8) % 15; q = (r + 15 - g8) % 15; }
        float a0 = Cc[p * 17 + rb], a1 = Cc[p * 17 + rb + 1];
        float c0 = Cc[q * 17 + rb], c1 = Cc[q * 17 + rb + 1];
        float sa = a0 * a0 + a1 * a1;
        float sb = c0 * c0 + c1 * c1;
        float sg = a0 * c0 + a1 * c1;
        sa += fshfl_xor(sa, 1); sb += fshfl_xor(sb, 1); sg += fshfl_xor(sg, 1);
        sa += fshfl_xor(sa, 2); sb += fshfl_xor(sb, 2); sg += fshfl_xor(sg, 2);
        sa += fshfl_xor(sa, 4); sb += fshfl_xor(sb, 4); sg += fshfl_xor(sg, 4);
        float dn  = sa * sb;
        float rel = (dn > 0.f) ? (sg * sg) / dn : 0.f;
        offmax = fmaxf(offmax, rel);
        if (rel > 1e-13f) {
          float u  = 0.5f * (sb - sa);
          float R  = sqrtf(u * u + sg * sg);
          float t  = sg / (u + ((u >= 0.f) ? R : -R));
          float ct = rsqrtf(1.f + t * t);
          float st = ct * t;
          Cc[p * 17 + rb]     = ct * a0 - st * c0;
          Cc[p * 17 + rb + 1] = ct * a1 - st * c1;
          Cc[q * 17 + rb]     = st * a0 + ct * c0;
          Cc[q * 17 + rb + 1] = st * a1 + ct * c1;
        }
        FENCE();
      }
      #pragma unroll
      for (int m = 1; m <= 32; m <<= 1) offmax = fmaxf(offmax, fshfl_xor(offmax, m));
      if (offmax < 1e-12f) break;
    }
  }

  // ---------------- Qb[k][j] = (V2^T w3)[k][j] * sqrt(clamp(lam2_k)) in regs
  // lane = (kq = lane>>2, jq = lane&3); per-lane norm of its column kq.
  float qv;
  const int kq = lane >> 2;
  const int jq = lane & 3;
  {
    float accq = 0.f, ss = 0.f;
    #pragma unroll 4
    for (int r = 0; r < 16; ++r) {
      float v = Cc[kq * 17 + r];
      accq += v * w3g[r * 4 + jq];
      ss   += v * v;
    }
    float lam = sqrtf(ss);
    float scl = ((lam > 0.f) ? (1.f / lam) : 0.f) * sqrtf(fmaxf(lam, 1e-4f));
    qv = accq * scl;
  }

  // ---------------- stage 3: one-sided Jacobi ON THE 16x4 FACTOR, with
  // accumulated rotations J. M3 = Q^T Q = J Sigma^2 J^T -> eigenvectors are
  // the columns of J. J[kq][jq] per lane (kq<4 meaningful).
  float jv = (kq == jq) ? 1.f : 0.f;
  {
    #define ROT3(P_, Q_) do {                                             \
      float w_ = fshfl_xor(qv, (P_) ^ (Q_));                              \
      float s1 = qv * qv, s2 = w_ * w_, s3 = qv * w_;                     \
      s1 += fshfl_xor(s1, 4);  s2 += fshfl_xor(s2, 4);  s3 += fshfl_xor(s3, 4);  \
      s1 += fshfl_xor(s1, 8);  s2 += fshfl_xor(s2, 8);  s3 += fshfl_xor(s3, 8);  \
      s1 += fshfl_xor(s1, 16); s2 += fshfl_xor(s2, 16); s3 += fshfl_xor(s3, 16); \
      s1 += fshfl_xor(s1, 32); s2 += fshfl_xor(s2, 32); s3 += fshfl_xor(s3, 32); \
      bool isp = (jq == (P_)), isq = (jq == (Q_));                        \
      float sa = isp ? s1 : s2;                                           \
      float sb = isp ? s2 : s1;                                           \
      float u_ = 0.5f * (sb - sa);                                        \
      float R_ = sqrtf(u_ * u_ + s3 * s3);                                \
      float dn_ = u_ + copysignf(fmaxf(R_, 1e-30f), u_);                  \
      float t_ = s3 / dn_;                                                \
      float ct = rsqrtf(1.f + t_ * t_);                                   \
      float st = ct * t_;                                                 \
      float wj_ = fshfl_xor(jv, (P_) ^ (Q_));                             \
      float nv  = isp ? (ct * qv - st * w_)  : (st * w_  + ct * qv);      \
      float nvj = isp ? (ct * jv - st * wj_) : (st * wj_ + ct * jv);      \
      if (isp | isq) { qv = nv; jv = nvj; }                               \
    } while (0)

    #pragma unroll 1
    for (int sweep = 0; sweep < 6; ++sweep) {
      ROT3(0,1); ROT3(2,3); ROT3(0,2); ROT3(1,3); ROT3(0,3); ROT3(1,2);
    }
    #undef ROT3
  }

  // ---------------- lambda_3 = ||col||^2, LogEig via J, FC, log_softmax
  {
    float ss = qv * qv;
    ss += fshfl_xor(ss, 4); ss += fshfl_xor(ss, 8);
    ss += fshfl_xor(ss, 16); ss += fshfl_xor(ss, 32);
    float lwv = logf(fmaxf(ss, 1e-10f));       // log eigenvalue of column jq
    if (kq < 4)  Pb[kq * 4 + jq] = jv;         // J, row-major 4x4
    if (kq == 0) Pb[16 + jq] = lwv;            // lanes 0..3: per-column loglam
    FENCE();

    float f = 0.f;
    if (lane < 16) {
      int i3 = lane >> 2, j3 = lane & 3;
      #pragma unroll
      for (int c = 0; c < 4; ++c)
        f += Pb[16 + c] * Pb[i3 * 4 + c] * Pb[j3 * 4 + c];
    }
    float t0 = 0.f, t1 = 0.f;
    if (lane < 16) { t0 = f * fcg[2 * lane]; t1 = f * fcg[2 * lane + 1]; }
    t0 += fshfl_xor(t0, 1); t1 += fshfl_xor(t1, 1);
    t0 += fshfl_xor(t0, 2); t1 += fshfl_xor(t1, 2);
    t0 += fshfl_xor(t0, 4); t1 += fshfl_xor(t1, 4);
    t0 += fshfl_xor(t0, 8); t1 += fshfl_xor(t1, 8);
    float mx  = fmaxf(t0, t1);
    float lse = mx + logf(expf(t0 - mx) + expf(t1 - mx));

    float* outFeat = outg + (size_t)B * 2;
    if (lane < 16) outFeat[(size_t)b * 16 + lane] = f;
    if (lane < 2)  outg[(size_t)b * 2 + lane] = (lane == 0 ? t0 : t1) - lse;
  }
}

extern "C" void kernel_launch(void* const* d_in, const int* in_sizes, int n_in,
                              void* d_out, int out_size, void* d_ws, size_t ws_size,
                              hipStream_t stream) {
  const float* x  = (const float*)d_in[0];
  const float* w1 = (const float*)d_in[1];
  const float* w2 = (const float*)d_in[2];
  const float* w3 = (const float*)d_in[3];
  const float* fc = (const float*)d_in[4];
  float* out = (float*)d_out;
  int B = in_sizes[0] / 1024;
  int grid = (B + 3) / 4;
  hipLaunchKernelGGL(spd_fused, dim3(grid), dim3(256), 0, stream,
                     x, w1, w2, w3, fc, out, B);
}

// Round 7
// 2227.467 us; speedup vs baseline: 1.5387x; 1.4065x over previous
//
#include <hip/hip_runtime.h>

// Wave-level LDS ordering fence: waits all outstanding LDS ops; "memory"
// clobber stops compiler reordering LDS accesses across it. Waves are fully
// independent (per-wave LDS slots, no shared weights in LDS) -> no barriers.
#define FENCE() asm volatile("s_waitcnt lgkmcnt(0)" ::: "memory")

__device__ __forceinline__ float fshfl_xor(float v, int m) {
  return __shfl_xor(v, m, 64);
}

// Raw single-instruction approx ops (v_sqrt_f32 / v_rcp_f32 / v_rsq_f32,
// ~1e-7 rel err): plenty for Jacobi rotation parameters and scale factors.
__device__ __forceinline__ float fsqrt(float x) { return __builtin_amdgcn_sqrtf(x); }
__device__ __forceinline__ float frcp (float x) { return __builtin_amdgcn_rcpf(x); }
__device__ __forceinline__ float frsq (float x) { return __builtin_amdgcn_rsqf(x); }

// One block = 256 threads = 4 waves, one 32x32 SPD matrix per wave.
// All-fp32. VALU-issue-bound (r6: VALUBusy ~100% @ 45% occupancy), so this
// round cuts instructions: incremental p/q (no %31 magic-div), raw approx
// sqrt/rcp/rsq, tighter sweep caps, stage-2 LDS ops vectorized to b64
// (stride 17 -> 18 for 8B alignment).
// LDS: 4*1536*4 = 24576 B/block; VGPR<=64.
__global__ __launch_bounds__(256, 8) void spd_fused(
    const float* __restrict__ xg,
    const float* __restrict__ w1g,
    const float* __restrict__ w2g,
    const float* __restrict__ w3g,
    const float* __restrict__ fcg,
    float* __restrict__ outg,
    int B)
{
  __shared__ float slot[4][1536];

  const int tid  = threadIdx.x;
  const int wid  = tid >> 6;
  const int lane = tid & 63;

  float* Cc = slot[wid];          // 1024: x -> M1(swizzled cols) -> M2/V2 (stride 18)
  float* Pb = slot[wid] + 1024;   // 512:  Ps (32x16) -> stage-3 J/lw scratch

  const long b = (long)blockIdx.x * 4 + wid;
  if (b >= B) return;

  // ---------------- load x -> Cc row-major [32][32]
  {
    const float4* xv = (const float4*)(xg + (size_t)b * 1024);
    float4* c4 = (float4*)Cc;
    #pragma unroll
    for (int jj = 0; jj < 4; ++jj) {
      int i4 = lane + 64 * jj;
      c4[i4] = xv[i4];
    }
  }
  FENCE();

  const int j = lane & 31;
  const int h = lane >> 5;

  // ---------------- Tmat = x * w1 in registers. T[e] = Tmat[16h+e][j].
  // Uses x symmetry: x[r][c] == x[c][r] -> read x rows as float4.
  float T[16];
  {
    #pragma unroll
    for (int e = 0; e < 16; ++e) T[e] = 0.f;
    const float4* c4 = (const float4*)Cc;
    #pragma unroll 4
    for (int c = 0; c < 32; ++c) {
      float wv = w1g[c * 32 + j];
      float4 x0 = c4[c * 8 + h * 4 + 0];
      float4 x1 = c4[c * 8 + h * 4 + 1];
      float4 x2 = c4[c * 8 + h * 4 + 2];
      float4 x3 = c4[c * 8 + h * 4 + 3];
      T[0]  += x0.x * wv; T[1]  += x0.y * wv; T[2]  += x0.z * wv; T[3]  += x0.w * wv;
      T[4]  += x1.x * wv; T[5]  += x1.y * wv; T[6]  += x1.z * wv; T[7]  += x1.w * wv;
      T[8]  += x2.x * wv; T[9]  += x2.y * wv; T[10] += x2.z * wv; T[11] += x2.w * wv;
      T[12] += x3.x * wv; T[13] += x3.y * wv; T[14] += x3.z * wv; T[15] += x3.w * wv;
    }
  }
  FENCE();   // all x reads complete before M1 overwrites Cc

  // ---------------- M1 = w1^T * Tmat -> Cc swizzled-quad column-major.
  // Column p, quad qd lives at p*32 + ((qd+p)&7)*4. Outer product over r
  // (r = 16h+e handled by this lane), halves combined via shfl_xor(32).
  {
    const float4* w14 = (const float4*)w1g;   // row r = w14[r*8 + 0..7]
    #pragma unroll
    for (int ih2 = 0; ih2 < 4; ++ih2) {       // i = 8*ih2 + u
      float acc[8];
      #pragma unroll
      for (int u = 0; u < 8; ++u) acc[u] = 0.f;
      #pragma unroll 4
      for (int e = 0; e < 16; ++e) {
        int r = 16 * h + e;
        float4 wA = w14[r * 8 + ih2 * 2];
        float4 wB = w14[r * 8 + ih2 * 2 + 1];
        float tv = T[e];
        acc[0] += wA.x * tv; acc[1] += wA.y * tv; acc[2] += wA.z * tv; acc[3] += wA.w * tv;
        acc[4] += wB.x * tv; acc[5] += wB.y * tv; acc[6] += wB.z * tv; acc[7] += wB.w * tv;
      }
      #pragma unroll
      for (int u = 0; u < 8; ++u) acc[u] += fshfl_xor(acc[u], 32);
      if (h == (ih2 & 1)) {
        int qd0 = 2 * ih2, qd1 = 2 * ih2 + 1;
        *(float4*)(Cc + j * 32 + (((qd0 + j) & 7) << 2)) =
            make_float4(acc[0], acc[1], acc[2], acc[3]);
        *(float4*)(Cc + j * 32 + (((qd1 + j) & 7) << 2)) =
            make_float4(acc[4], acc[5], acc[6], acc[7]);
      }
    }
  }
  FENCE();

  // ---------------- one-sided Jacobi, n=32 (16 pairs/round, 4 lanes/pair)
  {
    const int g4 = lane >> 2;
    const int c2 = (lane & 3) << 1;   // this lane handles quads c2, c2+1
    const int p_init = (g4 == 0) ? 31 : g4;
    const int q_init = (g4 == 0) ? 0  : 31 - g4;
    #pragma unroll 1
    for (int sweep = 0; sweep < 8; ++sweep) {
      float offmax = 0.f;
      int p = p_init, q = q_init;
      #pragma unroll 1
      for (int r = 0; r < 31; ++r) {
        const int pa0 = p * 32 + (((c2 + p) & 7) << 2);
        const int pa1 = p * 32 + (((c2 + 1 + p) & 7) << 2);
        const int qa0 = q * 32 + (((c2 + q) & 7) << 2);
        const int qa1 = q * 32 + (((c2 + 1 + q) & 7) << 2);
        float4 a0 = *(const float4*)(Cc + pa0);
        float4 a1 = *(const float4*)(Cc + pa1);
        float4 b0 = *(const float4*)(Cc + qa0);
        float4 b1 = *(const float4*)(Cc + qa1);
        float sa = a0.x*a0.x + a0.y*a0.y + a0.z*a0.z + a0.w*a0.w
                 + a1.x*a1.x + a1.y*a1.y + a1.z*a1.z + a1.w*a1.w;
        float sb = b0.x*b0.x + b0.y*b0.y + b0.z*b0.z + b0.w*b0.w
                 + b1.x*b1.x + b1.y*b1.y + b1.z*b1.z + b1.w*b1.w;
        float sg = a0.x*b0.x + a0.y*b0.y + a0.z*b0.z + a0.w*b0.w
                 + a1.x*b1.x + a1.y*b1.y + a1.z*b1.z + a1.w*b1.w;
        sa += fshfl_xor(sa, 1); sb += fshfl_xor(sb, 1); sg += fshfl_xor(sg, 1);
        sa += fshfl_xor(sa, 2); sb += fshfl_xor(sb, 2); sg += fshfl_xor(sg, 2);
        float rel = sg * sg * frcp(fmaxf(sa * sb, 1e-30f));
        offmax = fmaxf(offmax, rel);
        if (rel > 1e-13f) {
          float u  = 0.5f * (sb - sa);
          float R  = fsqrt(u * u + sg * sg);
          float t  = sg * frcp(u + ((u >= 0.f) ? R : -R));
          float ct = frsq(1.f + t * t);
          float st = ct * t;
          float4 n0, n1, m0, m1;
          n0.x = ct*a0.x - st*b0.x;  m0.x = st*a0.x + ct*b0.x;
          n0.y = ct*a0.y - st*b0.y;  m0.y = st*a0.y + ct*b0.y;
          n0.z = ct*a0.z - st*b0.z;  m0.z = st*a0.z + ct*b0.z;
          n0.w = ct*a0.w - st*b0.w;  m0.w = st*a0.w + ct*b0.w;
          n1.x = ct*a1.x - st*b1.x;  m1.x = st*a1.x + ct*b1.x;
          n1.y = ct*a1.y - st*b1.y;  m1.y = st*a1.y + ct*b1.y;
          n1.z = ct*a1.z - st*b1.z;  m1.z = st*a1.z + ct*b1.z;
          n1.w = ct*a1.w - st*b1.w;  m1.w = st*a1.w + ct*b1.w;
          *(float4*)(Cc + pa0) = n0; *(float4*)(Cc + pa1) = n1;
          *(float4*)(Cc + qa0) = m0; *(float4*)(Cc + qa1) = m1;
        }
        FENCE();
        // incremental round-robin update (replaces %31 magic-div sequences)
        p = (g4 == 0) ? 31 : ((p == 30) ? 0 : p + 1);
        q = (q == 30) ? 0 : q + 1;
      }
      #pragma unroll
      for (int m = 1; m <= 32; m <<= 1) offmax = fmaxf(offmax, fshfl_xor(offmax, m));
      if (offmax < 1e-11f) break;
    }
  }

  // ---------------- lambda_1 + ReEig + Ps = sqrt(clamp(lam1))*v1hat^T w2,
  // fused single pass over the column's 8 quads (no col[] register array).
  // Ps -> Pb (32x16, stride 16); M2 = Ps^T Ps later (diagonal folded in).
  {
    const int k1  = lane & 31;              // column owned by this lane
    const int jb4 = (lane >> 5) * 2;        // float4 col-block: jb = jb4*4
    const float4* w24 = (const float4*)w2g; // row r = w24[r*4 + 0..3]
    float acc[8];
    #pragma unroll
    for (int u = 0; u < 8; ++u) acc[u] = 0.f;
    float ss = 0.f;
    #pragma unroll 2
    for (int qd = 0; qd < 8; ++qd) {
      float4 v = *(const float4*)(Cc + k1 * 32 + (((qd + k1) & 7) << 2));
      ss += v.x*v.x + v.y*v.y + v.z*v.z + v.w*v.w;
      const int r0 = qd << 2;
      float4 wA, wB;
      wA = w24[(r0 + 0) * 4 + jb4]; wB = w24[(r0 + 0) * 4 + jb4 + 1];
      acc[0] += v.x * wA.x; acc[1] += v.x * wA.y; acc[2] += v.x * wA.z; acc[3] += v.x * wA.w;
      acc[4] += v.x * wB.x; acc[5] += v.x * wB.y; acc[6] += v.x * wB.z; acc[7] += v.x * wB.w;
      wA = w24[(r0 + 1) * 4 + jb4]; wB = w24[(r0 + 1) * 4 + jb4 + 1];
      acc[0] += v.y * wA.x; acc[1] += v.y * wA.y; acc[2] += v.y * wA.z; acc[3] += v.y * wA.w;
      acc[4] += v.y * wB.x; acc[5] += v.y * wB.y; acc[6] += v.y * wB.z; acc[7] += v.y * wB.w;
      wA = w24[(r0 + 2) * 4 + jb4]; wB = w24[(r0 + 2) * 4 + jb4 + 1];
      acc[0] += v.z * wA.x; acc[1] += v.z * wA.y; acc[2] += v.z * wA.z; acc[3] += v.z * wA.w;
      acc[4] += v.z * wB.x; acc[5] += v.z * wB.y; acc[6] += v.z * wB.z; acc[7] += v.z * wB.w;
      wA = w24[(r0 + 3) * 4 + jb4]; wB = w24[(r0 + 3) * 4 + jb4 + 1];
      acc[0] += v.w * wA.x; acc[1] += v.w * wA.y; acc[2] += v.w * wA.z; acc[3] += v.w * wA.w;
      acc[4] += v.w * wB.x; acc[5] += v.w * wB.y; acc[6] += v.w * wB.z; acc[7] += v.w * wB.w;
    }
    float lam = fsqrt(ss);
    float sc1 = (lam > 0.f) ? (fsqrt(fmaxf(lam, 1e-4f)) * frcp(lam)) : 0.f;
    #pragma unroll
    for (int u = 0; u < 8; ++u) acc[u] *= sc1;
    *(float4*)(Pb + k1 * 16 + jb4 * 4)     = make_float4(acc[0], acc[1], acc[2], acc[3]);
    *(float4*)(Pb + k1 * 16 + jb4 * 4 + 4) = make_float4(acc[4], acc[5], acc[6], acc[7]);
  }
  FENCE();

  // ---------------- M2 = Ps^T Ps -> Cc col-major (stride 18, even -> b64)
  {
    const int i0 = lane >> 4;     // 0..3
    const int j2 = lane & 15;
    float m2[4] = {0.f, 0.f, 0.f, 0.f};
    #pragma unroll 4
    for (int kk = 0; kk < 32; ++kk) {
      float pv = Pb[kk * 16 + j2];
      #pragma unroll
      for (int e = 0; e < 4; ++e)
        m2[e] += pv * Pb[kk * 16 + (e << 2) + i0];
    }
    #pragma unroll
    for (int e = 0; e < 4; ++e)
      Cc[j2 * 18 + (e << 2) + i0] = m2[e];
  }
  FENCE();

  // ---------------- one-sided Jacobi, n=16 (8 pairs/round, 8 lanes/pair)
  // Columns stride 18 (even): each lane's 2 rows are one ds_read/write_b64.
  {
    const int g8 = lane >> 3;
    const int rb = (lane & 7) * 2;
    const int p_init = (g8 == 0) ? 15 : g8;
    const int q_init = (g8 == 0) ? 0  : 15 - g8;
    #pragma unroll 1
    for (int sweep = 0; sweep < 6; ++sweep) {
      float offmax = 0.f;
      int p = p_init, q = q_init;
      #pragma unroll 1
      for (int r = 0; r < 15; ++r) {
        float2 av = *(const float2*)(Cc + p * 18 + rb);
        float2 cv = *(const float2*)(Cc + q * 18 + rb);
        float sa = av.x * av.x + av.y * av.y;
        float sb = cv.x * cv.x + cv.y * cv.y;
        float sg = av.x * cv.x + av.y * cv.y;
        sa += fshfl_xor(sa, 1); sb += fshfl_xor(sb, 1); sg += fshfl_xor(sg, 1);
        sa += fshfl_xor(sa, 2); sb += fshfl_xor(sb, 2); sg += fshfl_xor(sg, 2);
        sa += fshfl_xor(sa, 4); sb += fshfl_xor(sb, 4); sg += fshfl_xor(sg, 4);
        float rel = sg * sg * frcp(fmaxf(sa * sb, 1e-30f));
        offmax = fmaxf(offmax, rel);
        if (rel > 1e-13f) {
          float u  = 0.5f * (sb - sa);
          float R  = fsqrt(u * u + sg * sg);
          float t  = sg * frcp(u + ((u >= 0.f) ? R : -R));
          float ct = frsq(1.f + t * t);
          float st = ct * t;
          float2 nv, mv;
          nv.x = ct * av.x - st * cv.x;  mv.x = st * av.x + ct * cv.x;
          nv.y = ct * av.y - st * cv.y;  mv.y = st * av.y + ct * cv.y;
          *(float2*)(Cc + p * 18 + rb) = nv;
          *(float2*)(Cc + q * 18 + rb) = mv;
        }
        FENCE();
        p = (g8 == 0) ? 15 : ((p == 14) ? 0 : p + 1);
        q = (q == 14) ? 0 : q + 1;
      }
      #pragma unroll
      for (int m = 1; m <= 32; m <<= 1) offmax = fmaxf(offmax, fshfl_xor(offmax, m));
      if (offmax < 1e-11f) break;
    }
  }

  // ---------------- Qb[k][j] = (V2^T w3)[k][j] * sqrt(clamp(lam2_k)) in regs
  // lane = (kq = lane>>2, jq = lane&3); per-lane norm of its column kq.
  float qv;
  const int kq = lane >> 2;
  const int jq = lane & 3;
  {
    float accq = 0.f, ss = 0.f;
    #pragma unroll 4
    for (int r = 0; r < 16; ++r) {
      float v = Cc[kq * 18 + r];
      accq += v * w3g[r * 4 + jq];
      ss   += v * v;
    }
    float lam = fsqrt(ss);
    float scl = (lam > 0.f) ? (frcp(lam) * fsqrt(fmaxf(lam, 1e-4f))) : 0.f;
    qv = accq * scl;
  }

  // ---------------- stage 3: one-sided Jacobi ON THE 16x4 FACTOR, with
  // accumulated rotations J. M3 = Q^T Q = J Sigma^2 J^T -> eigenvectors are
  // the columns of J. J[kq][jq] per lane (kq<4 meaningful).
  float jv = (kq == jq) ? 1.f : 0.f;
  {
    #define ROT3(P_, Q_) do {                                             \
      float w_ = fshfl_xor(qv, (P_) ^ (Q_));                              \
      float s1 = qv * qv, s2 = w_ * w_, s3 = qv * w_;                     \
      s1 += fshfl_xor(s1, 4);  s2 += fshfl_xor(s2, 4);  s3 += fshfl_xor(s3, 4);  \
      s1 += fshfl_xor(s1, 8);  s2 += fshfl_xor(s2, 8);  s3 += fshfl_xor(s3, 8);  \
      s1 += fshfl_xor(s1, 16); s2 += fshfl_xor(s2, 16); s3 += fshfl_xor(s3, 16); \
      s1 += fshfl_xor(s1, 32); s2 += fshfl_xor(s2, 32); s3 += fshfl_xor(s3, 32); \
      bool isp = (jq == (P_)), isq = (jq == (Q_));                        \
      float sa = isp ? s1 : s2;                                           \
      float sb = isp ? s2 : s1;                                           \
      float u_ = 0.5f * (sb - sa);                                        \
      float R_ = fsqrt(u_ * u_ + s3 * s3);                                \
      float dn_ = u_ + copysignf(fmaxf(R_, 1e-30f), u_);                  \
      float t_ = s3 * frcp(dn_);                                          \
      float ct = frsq(1.f + t_ * t_);                                     \
      float st = ct * t_;                                                 \
      float wj_ = fshfl_xor(jv, (P_) ^ (Q_));                             \
      float nv  = isp ? (ct * qv - st * w_)  : (st * w_  + ct * qv);      \
      float nvj = isp ? (ct * jv - st * wj_) : (st * wj_ + ct * jv);      \
      if (isp | isq) { qv = nv; jv = nvj; }                               \
    } while (0)

    #pragma unroll 1
    for (int sweep = 0; sweep < 6; ++sweep) {
      ROT3(0,1); ROT3(2,3); ROT3(0,2); ROT3(1,3); ROT3(0,3); ROT3(1,2);
    }
    #undef ROT3
  }

  // ---------------- lambda_3 = ||col||^2, LogEig via J, FC, log_softmax
  {
    float ss = qv * qv;
    ss += fshfl_xor(ss, 4); ss += fshfl_xor(ss, 8);
    ss += fshfl_xor(ss, 16); ss += fshfl_xor(ss, 32);
    float lwv = logf(fmaxf(ss, 1e-10f));       // log eigenvalue of column jq
    if (kq < 4)  Pb[kq * 4 + jq] = jv;         // J, row-major 4x4
    if (kq == 0) Pb[16 + jq] = lwv;            // lanes 0..3: per-column loglam
    FENCE();

    float f = 0.f;
    if (lane < 16) {
      int i3 = lane >> 2, j3 = lane & 3;
      #pragma unroll
      for (int c = 0; c < 4; ++c)
        f += Pb[16 + c] * Pb[i3 * 4 + c] * Pb[j3 * 4 + c];
    }
    float t0 = 0.f, t1 = 0.f;
    if (lane < 16) { t0 = f * fcg[2 * lane]; t1 = f * fcg[2 * lane + 1]; }
    t0 += fshfl_xor(t0, 1); t1 += fshfl_xor(t1, 1);
    t0 += fshfl_xor(t0, 2); t1 += fshfl_xor(t1, 2);
    t0 += fshfl_xor(t0, 4); t1 += fshfl_xor(t1, 4);
    t0 += fshfl_xor(t0, 8); t1 += fshfl_xor(t1, 8);
    float mx  = fmaxf(t0, t1);
    float lse = mx + logf(expf(t0 - mx) + expf(t1 - mx));

    float* outFeat = outg + (size_t)B * 2;
    if (lane < 16) outFeat[(size_t)b * 16 + lane] = f;
    if (lane < 2)  outg[(size_t)b * 2 + lane] = (lane == 0 ? t0 : t1) - lse;
  }
}

extern "C" void kernel_launch(void* const* d_in, const int* in_sizes, int n_in,
                              void* d_out, int out_size, void* d_ws, size_t ws_size,
                              hipStream_t stream) {
  const float* x  = (const float*)d_in[0];
  const float* w1 = (const float*)d_in[1];
  const float* w2 = (const float*)d_in[2];
  const float* w3 = (const float*)d_in[3];
  const float* fc = (const float*)d_in[4];
  float* out = (float*)d_out;
  int B = in_sizes[0] / 1024;
  int grid = (B + 3) / 4;
  hipLaunchKernelGGL(spd_fused, dim3(grid), dim3(256), 0, stream,
                     x, w1, w2, w3, fc, out, B);
}